// Round 7
// baseline (757.715 us; speedup 1.0000x reference)
//
#include <hip/hip_runtime.h>
#include <hip/hip_bf16.h>

typedef __attribute__((ext_vector_type(8))) short bf16x8;
typedef __attribute__((ext_vector_type(4))) float f32x4;

#define EMB 256
#define HEADS 8
#define DH 32
#define SEQ 8192
#define BATCH 4
#define NROWS (SEQ*BATCH)
#define FFD 1024
#define DEPTH 4
#define QKVN 768
#define SCALE 0.42044820762685725f
#define NCHUNK 128
#define ROWS_PER_CHUNK (SEQ/NCHUNK)

static __device__ __forceinline__ float bf2f(ushort u){
  union { unsigned int i; float f; } x; x.i = ((unsigned int)u) << 16; return x.f;
}
static __device__ __forceinline__ ushort f2bf(float f){
  union { __hip_bfloat16 h; ushort u; } cv;
  cv.h = __float2bfloat16(f);
  return cv.u;
}
// tanh-form GELU via one v_exp. |err| <= ~3e-3, negligible vs 0.104 threshold.
static __device__ __forceinline__ float gelu_f(float v){
  float y = 0.7978845608028654f * (v + 0.044715f*v*v*v);
  float e = __expf(2.0f*y);
  return 0.5f*v*(1.0f + (1.0f - 2.0f/(e + 1.0f)));
}

// direct HBM->LDS 16B DMA. LDS dest is lane-linear; global src per-lane
// (pre-swizzled, rule #21 both-sides form — validated R4/R5, absmax unchanged).
static __device__ __forceinline__ void gload_lds16(const ushort* g, ushort* l){
  __builtin_amdgcn_global_load_lds(
      (const __attribute__((address_space(1))) unsigned int*)(uintptr_t)g,
      (__attribute__((address_space(3))) unsigned int*)(uintptr_t)l,
      16, 0, 0);
}

// ---------------- weight prep: transpose fp32 [K,N] -> bf16 [N,K] -------------
__global__ __launch_bounds__(256) void prep_weights(
    const float* __restrict__ Wq, const float* __restrict__ Wk,
    const float* __restrict__ Wv, const float* __restrict__ Wo,
    const float* __restrict__ W1, const float* __restrict__ W2,
    ushort* __restrict__ wqkv_t, ushort* __restrict__ wo_t,
    ushort* __restrict__ w1_t, ushort* __restrict__ w2_t)
{
  __shared__ float tile[32][33];
  int bid = blockIdx.x;
  int L = bid / 768, r = bid % 768;
  const float* src; ushort* dst; int K, N, tidx;
  if (r < 192){ int which = r >> 6; tidx = r & 63;
    src = (which==0?Wq:which==1?Wk:Wv) + (long)L*65536;
    dst = wqkv_t + (long)L*QKVN*EMB + which*EMB*EMB; K=256; N=256;
  } else if (r < 256){ tidx = r-192; src = Wo + (long)L*65536; dst = wo_t + (long)L*65536; K=256; N=256; }
  else if (r < 512){ tidx = r-256; src = W1 + (long)L*262144; dst = w1_t + (long)L*262144; K=256; N=1024; }
  else { tidx = r-512; src = W2 + (long)L*262144; dst = w2_t + (long)L*262144; K=1024; N=256; }
  int tn = N >> 5;
  int tk = tidx / tn, tj = tidx % tn;
  int k0 = tk*32, n0 = tj*32;
  int c = threadIdx.x & 31, r0 = threadIdx.x >> 5;
  #pragma unroll
  for (int i=0;i<4;i++){
    int rr = r0 + i*8;
    tile[rr][c] = src[(long)(k0+rr)*N + n0 + c];
  }
  __syncthreads();
  #pragma unroll
  for (int i=0;i<4;i++){
    int rr = r0 + i*8;
    dst[(long)(n0+rr)*K + k0 + c] = f2bf(tile[c][rr]);
  }
}

// ---------------- residual copy ----------------------------------------------
__global__ void copy_f4(const float4* __restrict__ src, float4* __restrict__ dst, int n4){
  int i = blockIdx.x*blockDim.x + threadIdx.x;
  int stride = gridDim.x*blockDim.x;
  for (; i < n4; i += stride) dst[i] = src[i];
}

// ---------------- layernorm: fp32 x -> bf16 h --------------------------------
__global__ __launch_bounds__(256) void ln_kernel(const float* __restrict__ x,
    const float* __restrict__ g, const float* __restrict__ bb,
    ushort* __restrict__ h)
{
  int wid = threadIdx.x >> 6, lane = threadIdx.x & 63;
  long row = (long)blockIdx.x*4 + wid;
  const float4 xv = *(const float4*)(x + row*EMB + lane*4);
  float s = xv.x+xv.y+xv.z+xv.w;
  float s2 = xv.x*xv.x+xv.y*xv.y+xv.z*xv.z+xv.w*xv.w;
  #pragma unroll
  for (int m=1;m<64;m<<=1){ s += __shfl_xor(s,m,64); s2 += __shfl_xor(s2,m,64); }
  float mean = s * (1.0f/EMB);
  float inv = rsqrtf(s2*(1.0f/EMB) - mean*mean + 1e-5f);
  float4 gv = *(const float4*)(g + lane*4);
  float4 bv = *(const float4*)(bb + lane*4);
  ushort4 o;
  o.x = f2bf((xv.x-mean)*inv*gv.x + bv.x);
  o.y = f2bf((xv.y-mean)*inv*gv.y + bv.y);
  o.z = f2bf((xv.z-mean)*inv*gv.z + bv.z);
  o.w = f2bf((xv.w-mean)*inv*gv.w + bv.w);
  *(ushort4*)(h + row*EMB + lane*4) = o;
}

// ---------------- GEMM: C[M,N] = A[M,K] @ Bt[N,K]^T (bf16 in, fp32 acc) ------
// 256xBN tile, BK=64, 8 waves (2Mx4N), dbuf LDS, chunk-XOR swizzle.
// T3/T4 schedule: counted vmcnt (never drain mid-loop), issue group s+2 after
// the consume-barrier of step s. LDS-bounce coalesced epilogue (R6).
// MODE 0: write bf16 C      MODE 1: xres += C + bias      MODE 2: bf16 gelu(C + bias)
template<int MODE, int BN>
__global__ __launch_bounds__(512, 2) void gemm_bt(
    const ushort* __restrict__ A, const ushort* __restrict__ Bt,
    int M, int N, int K,
    const float* __restrict__ bias,
    float* __restrict__ xres, ushort* __restrict__ outb)
{
  constexpr int BM = 256, BK = 64;
  constexpr int NF = BN/64;          // B n-frags per wave (2 or 4)
  __shared__ ushort LDSraw[2*BM*BK + 2*BN*BK];
  ushort* Abuf0 = LDSraw;
  ushort* Abuf1 = LDSraw + BM*BK;
  ushort* Bbuf0 = LDSraw + 2*BM*BK;
  ushort* Bbuf1 = LDSraw + 2*BM*BK + BN*BK;
  int t = threadIdx.x;
  int lane = t & 63, wid = t >> 6;
  int wr = wid >> 2, wc = wid & 3;          // 2 x 4 waves
  int wrb = wr*128, wcb = wc*(BN/4);
  long rowA0 = (long)blockIdx.x * BM;
  long colB0 = (long)blockIdx.y * BN;
  const ushort* gA[4]; int dA[4];
  #pragma unroll
  for (int i=0;i<4;i++){
    int row = i*64 + (t>>3);
    int clog = (t&7) ^ (row&7);
    gA[i] = A + (rowA0 + row)*(long)K + clog*8;
    dA[i] = (i*512 + t)*8;
  }
  const ushort* gB[NF]; int dB[NF];
  #pragma unroll
  for (int i=0;i<NF;i++){
    int row = i*64 + (t>>3);
    int clog = (t&7) ^ (row&7);
    gB[i] = Bt + (colB0 + row)*(long)K + clog*8;
    dB[i] = (i*512 + t)*8;
  }
  ushort* Ac = Abuf0; ushort* An = Abuf1;
  ushort* Bc = Bbuf0; ushort* Bn = Bbuf1;
  f32x4 acc[8][NF] = {};
  int fr = lane & 15, cr4 = lane >> 4, xr = fr & 7;
  int nsteps = K >> 6;   // >= 4 for all our shapes
  // prologue: issue groups for steps 0 and 1 (16/12 loads in flight)
  #pragma unroll
  for (int i=0;i<4;i++) gload_lds16(gA[i], Ac + dA[i]);
  #pragma unroll
  for (int i=0;i<NF;i++) gload_lds16(gB[i], Bc + dB[i]);
  #pragma unroll
  for (int i=0;i<4;i++) gload_lds16(gA[i] + 64, An + dA[i]);
  #pragma unroll
  for (int i=0;i<NF;i++) gload_lds16(gB[i] + 64, Bn + dB[i]);
  for (int s = 0; s < nsteps; ++s){
    // wait for step-s group only; keep step-(s+1) group in flight (T4)
    if (s < nsteps-1){
      if constexpr (NF==4) asm volatile("s_waitcnt vmcnt(8)" ::: "memory");
      else                 asm volatile("s_waitcnt vmcnt(6)" ::: "memory");
    } else {
      asm volatile("s_waitcnt vmcnt(0)" ::: "memory");
    }
    __syncthreads();                  // buf[cur] fully staged for all waves
    #pragma unroll
    for (int kk=0; kk<2; ++kk){
      int chunk = ((kk*4 + cr4) ^ xr) << 3;
      bf16x8 bv[NF];
      #pragma unroll
      for (int n=0;n<NF;n++)
        bv[n] = *(const bf16x8*)(Bc + (wcb + n*16 + fr)*BK + chunk);
      #pragma unroll
      for (int mh=0; mh<2; ++mh){
        bf16x8 av[4];
        #pragma unroll
        for (int m=0;m<4;m++)
          av[m] = *(const bf16x8*)(Ac + (wrb + (mh*4+m)*16 + fr)*BK + chunk);
        __builtin_amdgcn_s_setprio(1);
        #pragma unroll
        for (int m=0;m<4;m++){
          #pragma unroll
          for (int n=0;n<NF;n++)
            acc[mh*4+m][n] = __builtin_amdgcn_mfma_f32_16x16x32_bf16(av[m], bv[n], acc[mh*4+m][n], 0,0,0);
        }
        __builtin_amdgcn_s_setprio(0);
      }
    }
    __syncthreads();                  // all waves done reading buf[cur]
    if (s + 2 < nsteps){              // refill the buffer just consumed
      long koff = (long)(s+2) << 6;
      #pragma unroll
      for (int i=0;i<4;i++) gload_lds16(gA[i] + koff, Ac + dA[i]);
      #pragma unroll
      for (int i=0;i<NF;i++) gload_lds16(gB[i] + koff, Bc + dB[i]);
    }
    ushort* tp;
    tp = Ac; Ac = An; An = tp;
    tp = Bc; Bc = Bn; Bn = tp;
  }
  // -------- epilogue: LDS-bounce -> coalesced global stores --------
  constexpr int BNP = BN + 4;              // padded fp32 row stride (16B-aligned)
  float* bounce = (float*)LDSraw;          // staging LDS is dead now (vmcnt 0 drained)
  int fq = lane >> 4;
  int rdrow = t / (BN/4);
  int rdcol = (t % (BN/4)) * 4;
  constexpr int RPP = 512 / (BN/4);        // rows per read pass (16 or 8)
  #pragma unroll
  for (int r = 0; r < 4; ++r){             // 4 rounds of 64 rows
    __syncthreads();
    if (wr == (r>>1)){
      int mb = (r&1)*4;
      #pragma unroll
      for (int m4=0;m4<4;m4++){
        #pragma unroll
        for (int n=0;n<NF;n++){
          #pragma unroll
          for (int i=0;i<4;i++)
            bounce[(m4*16 + fq*4 + i)*BNP + wcb + n*16 + fr] = acc[mb+m4][n][i];
        }
      }
    }
    __syncthreads();
    long gr0 = rowA0 + r*64;
    #pragma unroll
    for (int p=0;p<64/RPP;p++){
      int lr = p*RPP + rdrow;
      long gr = gr0 + lr;
      long gc = colB0 + rdcol;
      float4 v = *(float4*)&bounce[lr*BNP + rdcol];
      if (MODE==0){
        ushort4 o; o.x=f2bf(v.x); o.y=f2bf(v.y); o.z=f2bf(v.z); o.w=f2bf(v.w);
        *(ushort4*)&outb[gr*N + gc] = o;
      } else if (MODE==1){
        const float4 bv4 = *(const float4*)&bias[gc];
        float4 xv = *(float4*)&xres[gr*N + gc];
        xv.x += v.x + bv4.x; xv.y += v.y + bv4.y;
        xv.z += v.z + bv4.z; xv.w += v.w + bv4.w;
        *(float4*)&xres[gr*N + gc] = xv;
      } else {
        const float4 bv4 = *(const float4*)&bias[gc];
        ushort4 o;
        o.x = f2bf(gelu_f(v.x + bv4.x)); o.y = f2bf(gelu_f(v.y + bv4.y));
        o.z = f2bf(gelu_f(v.z + bv4.z)); o.w = f2bf(gelu_f(v.w + bv4.w));
        *(ushort4*)&outb[gr*N + gc] = o;
      }
    }
  }
}

// ---------------- k-softmax column stats, chunked over n ----------------------
__global__ __launch_bounds__(256) void colstats_partial(const ushort* __restrict__ qkv,
    float* __restrict__ pmax, float* __restrict__ psum)
{
  int ch = blockIdx.x, b = blockIdx.y;
  int t = threadIdx.x;
  const ushort* base = qkv + ((long)b*SEQ + (long)ch*ROWS_PER_CHUNK)*QKVN + EMB + t;
  float m[4] = {-1e30f,-1e30f,-1e30f,-1e30f};
  float s[4] = {0.f,0.f,0.f,0.f};
  #pragma unroll 2
  for (int n = 0; n < ROWS_PER_CHUNK; n += 4){
    #pragma unroll
    for (int j=0;j<4;j++){
      float v = bf2f(base[(long)(n+j)*QKVN]) * SCALE;
      float m2 = fmaxf(m[j], v);
      s[j] = s[j]*__expf(m[j]-m2) + __expf(v-m2);
      m[j] = m2;
    }
  }
  float M = fmaxf(fmaxf(m[0],m[1]), fmaxf(m[2],m[3]));
  float S = s[0]*__expf(m[0]-M) + s[1]*__expf(m[1]-M)
          + s[2]*__expf(m[2]-M) + s[3]*__expf(m[3]-M);
  long idx = ((long)b*NCHUNK + ch)*EMB + t;
  pmax[idx] = M; psum[idx] = S;
}

__global__ __launch_bounds__(256) void colstats_reduce(const float* __restrict__ pmax,
    const float* __restrict__ psum, float* __restrict__ kmax, float* __restrict__ ksum)
{
  int b = blockIdx.x, t = threadIdx.x;
  const float* pm = pmax + (long)b*NCHUNK*EMB + t;
  const float* ps = psum + (long)b*NCHUNK*EMB + t;
  float m = -1e30f, s = 0.f;
  for (int c = 0; c < NCHUNK; ++c){
    float cm = pm[(long)c*EMB], cs = ps[(long)c*EMB];
    float m2 = fmaxf(m, cm);
    s = s*__expf(m-m2) + cs*__expf(cm-m2);
    m = m2;
  }
  kmax[b*EMB + t] = m;
  ksum[b*EMB + t] = s;
}

// ---------------- context partials: ctx_part[b][h][chunk][d][e] --------------
__global__ __launch_bounds__(256) void ctx_partial(
    const ushort* __restrict__ qkv, const float* __restrict__ kmax,
    float* __restrict__ ctx_part)
{
  constexpr int LT = 72;
  __shared__ ushort ekT[32*LT];
  __shared__ ushort vvT[32*LT];
  int ch = blockIdx.x, h = blockIdx.y, b = blockIdx.z;
  int t = threadIdx.x, lane = t & 63, wid = t >> 6;
  long nbase = (long)b*SEQ + ch*512;
  int lrow = t >> 2, lseg = (t & 3) << 3;
  float km[8];
  #pragma unroll
  for (int j=0;j<8;j++) km[j] = kmax[b*256 + h*DH + lseg + j];
  int wstep = wid & 1, wdr = (wid >> 1) << 4;
  f32x4 acc0 = {}, acc1 = {};
  int frow = lane & 15, g8 = (lane >> 4) << 3;
  for (int st = 0; st < 8; ++st){
    long n0 = nbase + st*64;
    const ushort* gk = qkv + (n0 + lrow)*QKVN + EMB + h*DH + lseg;
    uint4 kv = *(const uint4*)gk;
    uint4 vv = *(const uint4*)(gk + EMB);
    __syncthreads();
    const ushort* kp = (const ushort*)&kv;
    const ushort* vp = (const ushort*)&vv;
    #pragma unroll
    for (int j=0;j<8;j++){
      float f = bf2f(kp[j])*SCALE;
      ekT[(lseg+j)*LT + lrow] = f2bf(__expf(f - km[j]));
      vvT[(lseg+j)*LT + lrow] = vp[j];
    }
    __syncthreads();
    bf16x8 afr = *(const bf16x8*)(ekT + (wdr + frow)*LT + wstep*32 + g8);
    bf16x8 bf0 = *(const bf16x8*)(vvT + frow*LT + wstep*32 + g8);
    bf16x8 bf1 = *(const bf16x8*)(vvT + (16 + frow)*LT + wstep*32 + g8);
    acc0 = __builtin_amdgcn_mfma_f32_16x16x32_bf16(afr, bf0, acc0, 0,0,0);
    acc1 = __builtin_amdgcn_mfma_f32_16x16x32_bf16(afr, bf1, acc1, 0,0,0);
  }
  int fq = lane >> 4;
  long pb = (((long)(b*HEADS+h))*32 + (ch*2+wstep))*1024;
  #pragma unroll
  for (int i=0;i<4;i++){
    ctx_part[pb + (wdr + fq*4 + i)*32 + frow] = acc0[i];
    ctx_part[pb + (wdr + fq*4 + i)*32 + 16 + frow] = acc1[i];
  }
}

// ---------------- context reduce + 1/ksum + write transposed bf16 ------------
__global__ __launch_bounds__(256) void ctx_reduce(const float* __restrict__ ctx_part,
    const float* __restrict__ ksum, ushort* __restrict__ ctxT)
{
  int bh = blockIdx.x; int b = bh >> 3, h = bh & 7;
  int t = threadIdx.x; int d = t >> 3, e4 = (t & 7) << 2;
  const float* p = ctx_part + (long)bh*32768 + d*32 + e4;
  float sx=0, sy=0, sz=0, sw=0;
  for (int c=0;c<32;c++){
    const float4 v = *(const float4*)(p + c*1024);
    sx+=v.x; sy+=v.y; sz+=v.z; sw+=v.w;
  }
  float inv = 1.0f / ksum[b*256 + h*DH + d];
  long base = (long)bh*1024;
  ctxT[base + (e4+0)*32 + d] = f2bf(sx*inv);
  ctxT[base + (e4+1)*32 + d] = f2bf(sy*inv);
  ctxT[base + (e4+2)*32 + d] = f2bf(sz*inv);
  ctxT[base + (e4+3)*32 + d] = f2bf(sw*inv);
}

// ---------------- q-softmax @ ctx -> ao (bf16) -------------------------------
__global__ __launch_bounds__(256) void attn_out(
    const ushort* __restrict__ qkv, const ushort* __restrict__ ctxT,
    ushort* __restrict__ ao)
{
  __shared__ ushort sq[4][16][264];
  int t = threadIdx.x, lane = t & 63, wid = t >> 6;
  long row0 = (long)blockIdx.x*64 + wid*16;
  int b = (int)(row0 / SEQ);
  int fr = lane & 15, g = lane >> 4;
  bf16x8 cf[8][2];
  #pragma unroll
  for (int h=0;h<8;h++){
    #pragma unroll
    for (int eh=0;eh<2;eh++)
      cf[h][eh] = *(const bf16x8*)(ctxT + ((long)(b*8+h)*32 + eh*16 + fr)*32 + g*8);
  }
  long gr = row0 + fr;
  #pragma unroll
  for (int hh=0;hh<2;hh++){
    int h = g*2 + hh;
    const ushort* qp = qkv + gr*QKVN + h*DH;
    union { uint4 v[4]; ushort u[32]; } qq;
    qq.v[0]=*(const uint4*)qp; qq.v[1]=*(const uint4*)(qp+8);
    qq.v[2]=*(const uint4*)(qp+16); qq.v[3]=*(const uint4*)(qp+24);
    float f[32]; float m = -1e30f;
    #pragma unroll
    for (int j=0;j<32;j++){ f[j] = bf2f(qq.u[j])*SCALE; m = fmaxf(m, f[j]); }
    float ssum = 0.f;
    #pragma unroll
    for (int j=0;j<32;j++){ f[j] = __expf(f[j]-m); ssum += f[j]; }
    float inv = 1.0f/ssum;
    union { uint4 v[4]; ushort u[32]; } oo;
    #pragma unroll
    for (int j=0;j<32;j++) oo.u[j] = f2bf(f[j]*inv);
    ushort* dst = &sq[wid][fr][h*DH];
    #pragma unroll
    for (int c2=0;c2<4;c2++) *(uint4*)(dst + c2*8) = oo.v[c2];
  }
  __syncthreads();
  #pragma unroll
  for (int h=0;h<8;h++){
    bf16x8 af = *(const bf16x8*)(&sq[wid][fr][h*DH + g*8]);
    f32x4 z = {};
    f32x4 o0 = __builtin_amdgcn_mfma_f32_16x16x32_bf16(af, cf[h][0], z, 0,0,0);
    f32x4 o1 = __builtin_amdgcn_mfma_f32_16x16x32_bf16(af, cf[h][1], z, 0,0,0);
    #pragma unroll
    for (int i=0;i<4;i++){
      long r = row0 + g*4 + i;
      ao[r*EMB + h*DH + fr]      = f2bf(o0[i]);
      ao[r*EMB + h*DH + 16 + fr] = f2bf(o1[i]);
    }
  }
}

// -----------------------------------------------------------------------------
extern "C" void kernel_launch(void* const* d_in, const int* in_sizes, int n_in,
                              void* d_out, int out_size, void* d_ws, size_t ws_size,
                              hipStream_t stream)
{
  const float* x_in = (const float*)d_in[0];
  const float* Wq  = (const float*)d_in[1];
  const float* Wk  = (const float*)d_in[2];
  const float* Wv  = (const float*)d_in[3];
  const float* Wo  = (const float*)d_in[4];
  const float* bo  = (const float*)d_in[5];
  const float* ln1g = (const float*)d_in[6];
  const float* ln1b = (const float*)d_in[7];
  const float* W1  = (const float*)d_in[8];
  const float* b1  = (const float*)d_in[9];
  const float* W2  = (const float*)d_in[10];
  const float* b2  = (const float*)d_in[11];
  const float* ln2g = (const float*)d_in[12];
  const float* ln2b = (const float*)d_in[13];
  float* x = (float*)d_out;   // residual stream lives in d_out (fp32)

  char* ws = (char*)d_ws;
  ushort* h_buf  = (ushort*)ws;  ws += (long)NROWS*EMB*2;
  ushort* big    = (ushort*)ws;  ws += (long)NROWS*FFD*2;
  ushort* wqkv_t = (ushort*)ws;  ws += (long)DEPTH*QKVN*EMB*2;
  ushort* wo_t   = (ushort*)ws;  ws += (long)DEPTH*EMB*EMB*2;
  ushort* w1_t   = (ushort*)ws;  ws += (long)DEPTH*FFD*EMB*2;
  ushort* w2_t   = (ushort*)ws;  ws += (long)DEPTH*EMB*FFD*2;
  float*  kmax   = (float*)ws;   ws += (long)BATCH*EMB*4;
  float*  ksumv  = (float*)ws;   ws += (long)BATCH*EMB*4;
  float*  ctx_part = (float*)ws; ws += (long)BATCH*HEADS*32*1024*4;
  ushort* ctxT   = (ushort*)ws;  ws += (long)BATCH*HEADS*1024*2;
  float*  pmax   = (float*)ws;   ws += (long)BATCH*NCHUNK*EMB*4;
  float*  psum   = (float*)ws;   ws += (long)BATCH*NCHUNK*EMB*4;

  prep_weights<<<3072, 256, 0, stream>>>(Wq, Wk, Wv, Wo, W1, W2, wqkv_t, wo_t, w1_t, w2_t);
  copy_f4<<<2048, 256, 0, stream>>>((const float4*)x_in, (float4*)x, NROWS*EMB/4);

  ushort* qkv = big;
  ushort* ffb = big;
  for (int L = 0; L < DEPTH; ++L){
    ln_kernel<<<NROWS/4, 256, 0, stream>>>(x, ln1g + L*EMB, ln1b + L*EMB, h_buf);
    gemm_bt<0,128><<<dim3(NROWS/256, QKVN/128), 512, 0, stream>>>(
        h_buf, wqkv_t + (long)L*QKVN*EMB, NROWS, QKVN, EMB, nullptr, nullptr, qkv);
    colstats_partial<<<dim3(NCHUNK, BATCH), 256, 0, stream>>>(qkv, pmax, psum);
    colstats_reduce<<<BATCH, 256, 0, stream>>>(pmax, psum, kmax, ksumv);
    ctx_partial<<<dim3(16, HEADS, BATCH), 256, 0, stream>>>(qkv, kmax, ctx_part);
    ctx_reduce<<<32, 256, 0, stream>>>(ctx_part, ksumv, ctxT);
    attn_out<<<NROWS/64, 256, 0, stream>>>(qkv, ctxT, h_buf);
    gemm_bt<1,128><<<dim3(NROWS/256, EMB/128), 512, 0, stream>>>(
        h_buf, wo_t + (long)L*EMB*EMB, NROWS, EMB, EMB, bo + L*EMB, x, nullptr);
    ln_kernel<<<NROWS/4, 256, 0, stream>>>(x, ln2g + L*EMB, ln2b + L*EMB, h_buf);
    gemm_bt<2,256><<<dim3(NROWS/256, FFD/256), 512, 0, stream>>>(
        h_buf, w1_t + (long)L*FFD*EMB, NROWS, FFD, EMB, b1 + L*FFD, nullptr, ffb);
    gemm_bt<1,128><<<dim3(NROWS/256, EMB/128), 512, 0, stream>>>(
        ffb, w2_t + (long)L*EMB*FFD, NROWS, EMB, FFD, b2 + L*EMB, x, nullptr);
  }
}

// Round 8
// 656.601 us; speedup vs baseline: 1.1540x; 1.1540x over previous
//
#include <hip/hip_runtime.h>
#include <hip/hip_bf16.h>

typedef __attribute__((ext_vector_type(8))) short bf16x8;
typedef __attribute__((ext_vector_type(4))) float f32x4;

#define EMB 256
#define HEADS 8
#define DH 32
#define SEQ 8192
#define BATCH 4
#define NROWS (SEQ*BATCH)
#define FFD 1024
#define DEPTH 4
#define QKVN 768
#define SCALE 0.42044820762685725f
#define NCHUNK 128
#define ROWS_PER_CHUNK (SEQ/NCHUNK)

static __device__ __forceinline__ float bf2f(ushort u){
  union { unsigned int i; float f; } x; x.i = ((unsigned int)u) << 16; return x.f;
}
static __device__ __forceinline__ ushort f2bf(float f){
  union { __hip_bfloat16 h; ushort u; } cv;
  cv.h = __float2bfloat16(f);
  return cv.u;
}
// tanh-form GELU via one v_exp. |err| <= ~3e-3, negligible vs 0.104 threshold.
static __device__ __forceinline__ float gelu_f(float v){
  float y = 0.7978845608028654f * (v + 0.044715f*v*v*v);
  float e = __expf(2.0f*y);
  return 0.5f*v*(1.0f + (1.0f - 2.0f/(e + 1.0f)));
}

// direct HBM->LDS 16B DMA. LDS dest lane-linear; global src pre-swizzled
// (rule #21 both-sides form — validated R4-R6, absmax unchanged).
static __device__ __forceinline__ void gload_lds16(const ushort* g, ushort* l){
  __builtin_amdgcn_global_load_lds(
      (const __attribute__((address_space(1))) unsigned int*)(uintptr_t)g,
      (__attribute__((address_space(3))) unsigned int*)(uintptr_t)l,
      16, 0, 0);
}

// ---------------- weight prep: transpose fp32 [K,N] -> bf16 [N,K] -------------
__global__ __launch_bounds__(256) void prep_weights(
    const float* __restrict__ Wq, const float* __restrict__ Wk,
    const float* __restrict__ Wv, const float* __restrict__ Wo,
    const float* __restrict__ W1, const float* __restrict__ W2,
    ushort* __restrict__ wqkv_t, ushort* __restrict__ wo_t,
    ushort* __restrict__ w1_t, ushort* __restrict__ w2_t)
{
  __shared__ float tile[32][33];
  int bid = blockIdx.x;
  int L = bid / 768, r = bid % 768;
  const float* src; ushort* dst; int K, N, tidx;
  if (r < 192){ int which = r >> 6; tidx = r & 63;
    src = (which==0?Wq:which==1?Wk:Wv) + (long)L*65536;
    dst = wqkv_t + (long)L*QKVN*EMB + which*EMB*EMB; K=256; N=256;
  } else if (r < 256){ tidx = r-192; src = Wo + (long)L*65536; dst = wo_t + (long)L*65536; K=256; N=256; }
  else if (r < 512){ tidx = r-256; src = W1 + (long)L*262144; dst = w1_t + (long)L*262144; K=256; N=1024; }
  else { tidx = r-512; src = W2 + (long)L*262144; dst = w2_t + (long)L*262144; K=1024; N=256; }
  int tn = N >> 5;
  int tk = tidx / tn, tj = tidx % tn;
  int k0 = tk*32, n0 = tj*32;
  int c = threadIdx.x & 31, r0 = threadIdx.x >> 5;
  #pragma unroll
  for (int i=0;i<4;i++){
    int rr = r0 + i*8;
    tile[rr][c] = src[(long)(k0+rr)*N + n0 + c];
  }
  __syncthreads();
  #pragma unroll
  for (int i=0;i<4;i++){
    int rr = r0 + i*8;
    dst[(long)(n0+rr)*K + k0 + c] = f2bf(tile[c][rr]);
  }
}

// ---------------- layernorm (layer-0 prologue only) ---------------------------
__global__ __launch_bounds__(256) void ln_kernel(const float* __restrict__ x,
    const float* __restrict__ g, const float* __restrict__ bb,
    ushort* __restrict__ h)
{
  int wid = threadIdx.x >> 6, lane = threadIdx.x & 63;
  long row = (long)blockIdx.x*4 + wid;
  const float4 xv = *(const float4*)(x + row*EMB + lane*4);
  float s = xv.x+xv.y+xv.z+xv.w;
  float s2 = xv.x*xv.x+xv.y*xv.y+xv.z*xv.z+xv.w*xv.w;
  #pragma unroll
  for (int m=1;m<64;m<<=1){ s += __shfl_xor(s,m,64); s2 += __shfl_xor(s2,m,64); }
  float mean = s * (1.0f/EMB);
  float inv = rsqrtf(s2*(1.0f/EMB) - mean*mean + 1e-5f);
  float4 gv = *(const float4*)(g + lane*4);
  float4 bv = *(const float4*)(bb + lane*4);
  ushort4 o;
  o.x = f2bf((xv.x-mean)*inv*gv.x + bv.x);
  o.y = f2bf((xv.y-mean)*inv*gv.y + bv.y);
  o.z = f2bf((xv.z-mean)*inv*gv.z + bv.z);
  o.w = f2bf((xv.w-mean)*inv*gv.w + bv.w);
  *(ushort4*)(h + row*EMB + lane*4) = o;
}

// ---------------- GEMM: C[M,N] = A[M,K] @ Bt[N,K]^T (bf16 in, fp32 acc) ------
// BMxBN tile, BK=64, 8 waves (2Mx4N), dbuf LDS, chunk-XOR swizzle, R6 schedule
// (spread prefetch during compute + setprio), LDS-bounce coalesced epilogue.
// MODE 0: bf16 C out
// MODE 2: bf16 gelu(C+bias) out
// MODE 3: x_out = x_in + C + bias (fp32) AND h_out = LN(x_out) bf16. BN==256.
template<int MODE, int BM, int BN>
__global__ __launch_bounds__(512, 2) void gemm_bt(
    const ushort* __restrict__ A, const ushort* __restrict__ Bt,
    int M, int N, int K,
    const float* __restrict__ bias,
    const float* __restrict__ xin, float* __restrict__ xout,
    ushort* __restrict__ outb,
    const float* __restrict__ lng, const float* __restrict__ lnb)
{
  constexpr int BK = 64;
  constexpr int NF = BN/64;          // B n-frags per wave (2 or 4)
  constexpr int MR = BM/32;          // A m-frags per wave (4 or 8)
  constexpr int MH = MR/4;           // mh sub-phases (1 or 2)
  constexpr int AI = BM/64;          // A staging issues (2 or 4)
  constexpr int TI = AI + NF;        // total issues per step
  constexpr int NPH = 2*MH;          // sub-phases per step
  __shared__ ushort LDSraw[2*BM*BK + 2*BN*BK];
  ushort* Abuf0 = LDSraw;
  ushort* Abuf1 = LDSraw + BM*BK;
  ushort* Bbuf0 = LDSraw + 2*BM*BK;
  ushort* Bbuf1 = LDSraw + 2*BM*BK + BN*BK;
  int t = threadIdx.x;
  int lane = t & 63, wid = t >> 6;
  int wr = wid >> 2, wc = wid & 3;          // 2 x 4 waves
  int wrb = wr*(BM/2), wcb = wc*(BN/4);
  long rowA0 = (long)blockIdx.x * BM;
  long colB0 = (long)blockIdx.y * BN;
  const ushort* gA[AI]; int dA[AI];
  #pragma unroll
  for (int i=0;i<AI;i++){
    int row = i*64 + (t>>3);
    int clog = (t&7) ^ (row&7);
    gA[i] = A + (rowA0 + row)*(long)K + clog*8;
    dA[i] = (i*512 + t)*8;
  }
  const ushort* gB[NF]; int dB[NF];
  #pragma unroll
  for (int i=0;i<NF;i++){
    int row = i*64 + (t>>3);
    int clog = (t&7) ^ (row&7);
    gB[i] = Bt + (colB0 + row)*(long)K + clog*8;
    dB[i] = (i*512 + t)*8;
  }
  ushort* Ac = Abuf0; ushort* An = Abuf1;
  ushort* Bc = Bbuf0; ushort* Bn = Bbuf1;
  f32x4 acc[MR][NF] = {};
  int fr = lane & 15, cr4 = lane >> 4, xr = fr & 7;
  int nsteps = K >> 6;
  // prologue: stage step 0
  #pragma unroll
  for (int i=0;i<AI;i++) gload_lds16(gA[i], Ac + dA[i]);
  #pragma unroll
  for (int i=0;i<NF;i++) gload_lds16(gB[i], Bc + dB[i]);
  asm volatile("s_waitcnt vmcnt(0)" ::: "memory");
  __syncthreads();
  for (int s = 0; s < nsteps; ++s){
    bool pf = (s+1 < nsteps);
    long knext = (long)(s+1) << 6;
    #pragma unroll
    for (int kk=0; kk<2; ++kk){
      int chunk = ((kk*4 + cr4) ^ xr) << 3;
      bf16x8 bv[NF];
      #pragma unroll
      for (int n=0;n<NF;n++)
        bv[n] = *(const bf16x8*)(Bc + (wcb + n*16 + fr)*BK + chunk);
      #pragma unroll
      for (int mh=0; mh<MH; ++mh){
        int sp = kk*MH + mh;
        bf16x8 av[4];
        #pragma unroll
        for (int m=0;m<4;m++)
          av[m] = *(const bf16x8*)(Ac + (wrb + (mh*4+m)*16 + fr)*BK + chunk);
        if (pf){
          #pragma unroll
          for (int j=0;j<TI;j++){
            if (j*NPH >= sp*TI && j*NPH < (sp+1)*TI){
              if (j < AI) gload_lds16(gA[j]+knext, An+dA[j]);
              else        gload_lds16(gB[j-AI]+knext, Bn+dB[j-AI]);
            }
          }
        }
        __builtin_amdgcn_s_setprio(1);
        #pragma unroll
        for (int m=0;m<4;m++){
          #pragma unroll
          for (int n=0;n<NF;n++)
            acc[mh*4+m][n] = __builtin_amdgcn_mfma_f32_16x16x32_bf16(av[m], bv[n], acc[mh*4+m][n], 0,0,0);
        }
        __builtin_amdgcn_s_setprio(0);
      }
    }
    asm volatile("s_waitcnt vmcnt(0)" ::: "memory");
    __syncthreads();
    ushort* tp;
    tp = Ac; Ac = An; An = tp;
    tp = Bc; Bc = Bn; Bn = tp;
  }
  // -------- epilogue: LDS-bounce -> coalesced stores (+ fused LN for MODE3) ---
  constexpr int BNP = BN + 4;              // padded fp32 row stride
  float* bounce = (float*)LDSraw;
  int fq = lane >> 4;
  int rdrow = t / (BN/4);
  int rdcol = (t % (BN/4)) * 4;
  constexpr int RPP = 512 / (BN/4);        // rows per read pass (16 or 8)
  constexpr int ROUNDS = BM/64;
  #pragma unroll
  for (int r = 0; r < ROUNDS; ++r){        // rounds of 64 rows
    __syncthreads();
    if (wr == r/(ROUNDS/2 > 0 ? ROUNDS/2 : 1)){
      int mb = (ROUNDS==4) ? (r&1)*4 : 0;
      #pragma unroll
      for (int m4=0;m4<4;m4++){
        #pragma unroll
        for (int n=0;n<NF;n++){
          #pragma unroll
          for (int i=0;i<4;i++)
            bounce[(m4*16 + fq*4 + i)*BNP + wcb + n*16 + fr] = acc[mb+m4][n][i];
        }
      }
    }
    __syncthreads();
    long gr0 = rowA0 + r*64;
    #pragma unroll
    for (int p=0;p<64/RPP;p++){
      int lr = p*RPP + rdrow;
      long gr = gr0 + lr;
      long gc = colB0 + rdcol;
      float4 v = *(float4*)&bounce[lr*BNP + rdcol];
      if (MODE==0){
        ushort4 o; o.x=f2bf(v.x); o.y=f2bf(v.y); o.z=f2bf(v.z); o.w=f2bf(v.w);
        *(ushort4*)&outb[gr*N + gc] = o;
      } else if (MODE==2){
        const float4 bv4 = *(const float4*)&bias[gc];
        ushort4 o;
        o.x = f2bf(gelu_f(v.x + bv4.x)); o.y = f2bf(gelu_f(v.y + bv4.y));
        o.z = f2bf(gelu_f(v.z + bv4.z)); o.w = f2bf(gelu_f(v.w + bv4.w));
        *(ushort4*)&outb[gr*N + gc] = o;
      } else {  // MODE 3: residual add + fused LayerNorm (BN==256, 1 wave/row)
        const float4 bv4 = *(const float4*)&bias[gc];
        const float4 xo  = *(const float4*)&xin[gr*N + gc];
        v.x += bv4.x + xo.x; v.y += bv4.y + xo.y;
        v.z += bv4.z + xo.z; v.w += bv4.w + xo.w;
        *(float4*)&xout[gr*N + gc] = v;
        float s1 = v.x+v.y+v.z+v.w;
        float s2 = v.x*v.x+v.y*v.y+v.z*v.z+v.w*v.w;
        #pragma unroll
        for (int mm=1;mm<64;mm<<=1){ s1 += __shfl_xor(s1,mm,64); s2 += __shfl_xor(s2,mm,64); }
        float mean = s1 * (1.0f/EMB);
        float inv = rsqrtf(s2*(1.0f/EMB) - mean*mean + 1e-5f);
        const float4 g4 = *(const float4*)&lng[gc];
        const float4 b4 = *(const float4*)&lnb[gc];
        ushort4 o;
        o.x = f2bf((v.x-mean)*inv*g4.x + b4.x);
        o.y = f2bf((v.y-mean)*inv*g4.y + b4.y);
        o.z = f2bf((v.z-mean)*inv*g4.z + b4.z);
        o.w = f2bf((v.w-mean)*inv*g4.w + b4.w);
        *(ushort4*)&outb[gr*EMB + gc] = o;
      }
    }
  }
}

// ---------------- k-softmax column stats, chunked over n ----------------------
__global__ __launch_bounds__(256) void colstats_partial(const ushort* __restrict__ qkv,
    float* __restrict__ pmax, float* __restrict__ psum)
{
  int ch = blockIdx.x, b = blockIdx.y;
  int t = threadIdx.x;
  const ushort* base = qkv + ((long)b*SEQ + (long)ch*ROWS_PER_CHUNK)*QKVN + EMB + t;
  float m[4] = {-1e30f,-1e30f,-1e30f,-1e30f};
  float s[4] = {0.f,0.f,0.f,0.f};
  #pragma unroll 2
  for (int n = 0; n < ROWS_PER_CHUNK; n += 4){
    #pragma unroll
    for (int j=0;j<4;j++){
      float v = bf2f(base[(long)(n+j)*QKVN]) * SCALE;
      float m2 = fmaxf(m[j], v);
      s[j] = s[j]*__expf(m[j]-m2) + __expf(v-m2);
      m[j] = m2;
    }
  }
  float M = fmaxf(fmaxf(m[0],m[1]), fmaxf(m[2],m[3]));
  float S = s[0]*__expf(m[0]-M) + s[1]*__expf(m[1]-M)
          + s[2]*__expf(m[2]-M) + s[3]*__expf(m[3]-M);
  long idx = ((long)b*NCHUNK + ch)*EMB + t;
  pmax[idx] = M; psum[idx] = S;
}

__global__ __launch_bounds__(256) void colstats_reduce(const float* __restrict__ pmax,
    const float* __restrict__ psum, float* __restrict__ kmax, float* __restrict__ ksum)
{
  int b = blockIdx.x, t = threadIdx.x;
  const float* pm = pmax + (long)b*NCHUNK*EMB + t;
  const float* ps = psum + (long)b*NCHUNK*EMB + t;
  float m = -1e30f, s = 0.f;
  for (int c = 0; c < NCHUNK; ++c){
    float cm = pm[(long)c*EMB], cs = ps[(long)c*EMB];
    float m2 = fmaxf(m, cm);
    s = s*__expf(m-m2) + cs*__expf(cm-m2);
    m = m2;
  }
  kmax[b*EMB + t] = m;
  ksum[b*EMB + t] = s;
}

// ---------------- context partials: ctx_part[b][h][chunk][d][e] --------------
__global__ __launch_bounds__(256) void ctx_partial(
    const ushort* __restrict__ qkv, const float* __restrict__ kmax,
    float* __restrict__ ctx_part)
{
  constexpr int LT = 72;
  __shared__ ushort ekT[32*LT];
  __shared__ ushort vvT[32*LT];
  int ch = blockIdx.x, h = blockIdx.y, b = blockIdx.z;
  int t = threadIdx.x, lane = t & 63, wid = t >> 6;
  long nbase = (long)b*SEQ + ch*512;
  int lrow = t >> 2, lseg = (t & 3) << 3;
  float km[8];
  #pragma unroll
  for (int j=0;j<8;j++) km[j] = kmax[b*256 + h*DH + lseg + j];
  int wstep = wid & 1, wdr = (wid >> 1) << 4;
  f32x4 acc0 = {}, acc1 = {};
  int frow = lane & 15, g8 = (lane >> 4) << 3;
  for (int st = 0; st < 8; ++st){
    long n0 = nbase + st*64;
    const ushort* gk = qkv + (n0 + lrow)*QKVN + EMB + h*DH + lseg;
    uint4 kv = *(const uint4*)gk;
    uint4 vv = *(const uint4*)(gk + EMB);
    __syncthreads();
    const ushort* kp = (const ushort*)&kv;
    const ushort* vp = (const ushort*)&vv;
    #pragma unroll
    for (int j=0;j<8;j++){
      float f = bf2f(kp[j])*SCALE;
      ekT[(lseg+j)*LT + lrow] = f2bf(__expf(f - km[j]));
      vvT[(lseg+j)*LT + lrow] = vp[j];
    }
    __syncthreads();
    bf16x8 afr = *(const bf16x8*)(ekT + (wdr + frow)*LT + wstep*32 + g8);
    bf16x8 bf0 = *(const bf16x8*)(vvT + frow*LT + wstep*32 + g8);
    bf16x8 bf1 = *(const bf16x8*)(vvT + (16 + frow)*LT + wstep*32 + g8);
    acc0 = __builtin_amdgcn_mfma_f32_16x16x32_bf16(afr, bf0, acc0, 0,0,0);
    acc1 = __builtin_amdgcn_mfma_f32_16x16x32_bf16(afr, bf1, acc1, 0,0,0);
  }
  int fq = lane >> 4;
  long pb = (((long)(b*HEADS+h))*32 + (ch*2+wstep))*1024;
  #pragma unroll
  for (int i=0;i<4;i++){
    ctx_part[pb + (wdr + fq*4 + i)*32 + frow] = acc0[i];
    ctx_part[pb + (wdr + fq*4 + i)*32 + 16 + frow] = acc1[i];
  }
}

// ---------------- context reduce + 1/ksum + write transposed bf16 ------------
__global__ __launch_bounds__(256) void ctx_reduce(const float* __restrict__ ctx_part,
    const float* __restrict__ ksum, ushort* __restrict__ ctxT)
{
  int bh = blockIdx.x; int b = bh >> 3, h = bh & 7;
  int t = threadIdx.x; int d = t >> 3, e4 = (t & 7) << 2;
  const float* p = ctx_part + (long)bh*32768 + d*32 + e4;
  float sx=0, sy=0, sz=0, sw=0;
  for (int c=0;c<32;c++){
    const float4 v = *(const float4*)(p + c*1024);
    sx+=v.x; sy+=v.y; sz+=v.z; sw+=v.w;
  }
  float inv = 1.0f / ksum[b*256 + h*DH + d];
  long base = (long)bh*1024;
  ctxT[base + (e4+0)*32 + d] = f2bf(sx*inv);
  ctxT[base + (e4+1)*32 + d] = f2bf(sy*inv);
  ctxT[base + (e4+2)*32 + d] = f2bf(sz*inv);
  ctxT[base + (e4+3)*32 + d] = f2bf(sw*inv);
}

// ---------------- q-softmax @ ctx -> ao (bf16) -------------------------------
__global__ __launch_bounds__(256) void attn_out(
    const ushort* __restrict__ qkv, const ushort* __restrict__ ctxT,
    ushort* __restrict__ ao)
{
  __shared__ ushort sq[4][16][264];
  int t = threadIdx.x, lane = t & 63, wid = t >> 6;
  long row0 = (long)blockIdx.x*64 + wid*16;
  int b = (int)(row0 / SEQ);
  int fr = lane & 15, g = lane >> 4;
  bf16x8 cf[8][2];
  #pragma unroll
  for (int h=0;h<8;h++){
    #pragma unroll
    for (int eh=0;eh<2;eh++)
      cf[h][eh] = *(const bf16x8*)(ctxT + ((long)(b*8+h)*32 + eh*16 + fr)*32 + g*8);
  }
  long gr = row0 + fr;
  #pragma unroll
  for (int hh=0;hh<2;hh++){
    int h = g*2 + hh;
    const ushort* qp = qkv + gr*QKVN + h*DH;
    union { uint4 v[4]; ushort u[32]; } qq;
    qq.v[0]=*(const uint4*)qp; qq.v[1]=*(const uint4*)(qp+8);
    qq.v[2]=*(const uint4*)(qp+16); qq.v[3]=*(const uint4*)(qp+24);
    float f[32]; float m = -1e30f;
    #pragma unroll
    for (int j=0;j<32;j++){ f[j] = bf2f(qq.u[j])*SCALE; m = fmaxf(m, f[j]); }
    float ssum = 0.f;
    #pragma unroll
    for (int j=0;j<32;j++){ f[j] = __expf(f[j]-m); ssum += f[j]; }
    float inv = 1.0f/ssum;
    union { uint4 v[4]; ushort u[32]; } oo;
    #pragma unroll
    for (int j=0;j<32;j++) oo.u[j] = f2bf(f[j]*inv);
    ushort* dst = &sq[wid][fr][h*DH];
    #pragma unroll
    for (int c2=0;c2<4;c2++) *(uint4*)(dst + c2*8) = oo.v[c2];
  }
  __syncthreads();
  #pragma unroll
  for (int h=0;h<8;h++){
    bf16x8 af = *(const bf16x8*)(&sq[wid][fr][h*DH + g*8]);
    f32x4 z = {};
    f32x4 o0 = __builtin_amdgcn_mfma_f32_16x16x32_bf16(af, cf[h][0], z, 0,0,0);
    f32x4 o1 = __builtin_amdgcn_mfma_f32_16x16x32_bf16(af, cf[h][1], z, 0,0,0);
    #pragma unroll
    for (int i=0;i<4;i++){
      long r = row0 + g*4 + i;
      ao[r*EMB + h*DH + fr]      = f2bf(o0[i]);
      ao[r*EMB + h*DH + 16 + fr] = f2bf(o1[i]);
    }
  }
}

// -----------------------------------------------------------------------------
extern "C" void kernel_launch(void* const* d_in, const int* in_sizes, int n_in,
                              void* d_out, int out_size, void* d_ws, size_t ws_size,
                              hipStream_t stream)
{
  const float* x_in = (const float*)d_in[0];
  const float* Wq  = (const float*)d_in[1];
  const float* Wk  = (const float*)d_in[2];
  const float* Wv  = (const float*)d_in[3];
  const float* Wo  = (const float*)d_in[4];
  const float* bo  = (const float*)d_in[5];
  const float* ln1g = (const float*)d_in[6];
  const float* ln1b = (const float*)d_in[7];
  const float* W1  = (const float*)d_in[8];
  const float* b1  = (const float*)d_in[9];
  const float* W2  = (const float*)d_in[10];
  const float* b2  = (const float*)d_in[11];
  const float* ln2g = (const float*)d_in[12];
  const float* ln2b = (const float*)d_in[13];
  float* x = (float*)d_out;   // residual stream lives in d_out (fp32)

  char* ws = (char*)d_ws;
  ushort* h_buf  = (ushort*)ws;  ws += (long)NROWS*EMB*2;   // LN out / attn out (shared)
  ushort* big    = (ushort*)ws;  ws += (long)NROWS*FFD*2;   // qkv then ff
  ushort* wqkv_t = (ushort*)ws;  ws += (long)DEPTH*QKVN*EMB*2;
  ushort* wo_t   = (ushort*)ws;  ws += (long)DEPTH*EMB*EMB*2;
  ushort* w1_t   = (ushort*)ws;  ws += (long)DEPTH*FFD*EMB*2;
  ushort* w2_t   = (ushort*)ws;  ws += (long)DEPTH*EMB*FFD*2;
  float*  kmax   = (float*)ws;   ws += (long)BATCH*EMB*4;
  float*  ksumv  = (float*)ws;   ws += (long)BATCH*EMB*4;
  float*  ctx_part = (float*)ws; ws += (long)BATCH*HEADS*32*1024*4;
  ushort* ctxT   = (ushort*)ws;  ws += (long)BATCH*HEADS*1024*2;
  float*  pmax   = (float*)ws;   ws += (long)BATCH*NCHUNK*EMB*4;
  float*  psum   = (float*)ws;   ws += (long)BATCH*NCHUNK*EMB*4;

  prep_weights<<<3072, 256, 0, stream>>>(Wq, Wk, Wv, Wo, W1, W2, wqkv_t, wo_t, w1_t, w2_t);
  // layer-0 LN1 (only standalone LN left; later LNs are fused into epilogues)
  ln_kernel<<<NROWS/4, 256, 0, stream>>>(x_in, ln1g, ln1b, h_buf);

  ushort* qkv = big;
  ushort* ffb = big;
  for (int L = 0; L < DEPTH; ++L){
    // QKV projection (h -> qkv)
    gemm_bt<0,256,128><<<dim3(NROWS/256, QKVN/128), 512, 0, stream>>>(
        h_buf, wqkv_t + (long)L*QKVN*EMB, NROWS, QKVN, EMB,
        nullptr, nullptr, nullptr, qkv, nullptr, nullptr);
    colstats_partial<<<dim3(NCHUNK, BATCH), 256, 0, stream>>>(qkv, pmax, psum);
    colstats_reduce<<<BATCH, 256, 0, stream>>>(pmax, psum, kmax, ksumv);
    ctx_partial<<<dim3(16, HEADS, BATCH), 256, 0, stream>>>(qkv, kmax, ctx_part);
    ctx_reduce<<<32, 256, 0, stream>>>(ctx_part, ksumv, ctxT);
    attn_out<<<NROWS/64, 256, 0, stream>>>(qkv, ctxT, h_buf);
    // Wo + residual + fused LN2 -> x (fp32) and h2 (bf16, in-place in h_buf)
    gemm_bt<3,128,256><<<dim3(NROWS/128, 1), 512, 0, stream>>>(
        h_buf, wo_t + (long)L*EMB*EMB, NROWS, EMB, EMB,
        bo + L*EMB, (L==0 ? x_in : x), x, h_buf,
        ln2g + L*EMB, ln2b + L*EMB);
    // FF up + gelu
    gemm_bt<2,256,256><<<dim3(NROWS/256, FFD/256), 512, 0, stream>>>(
        h_buf, w1_t + (long)L*FFD*EMB, NROWS, FFD, EMB,
        b1 + L*FFD, nullptr, nullptr, ffb, nullptr, nullptr);
    // FF down + residual + fused LN1 of next layer -> x and h1_next (h_buf)
    int Ln = (L+1 < DEPTH) ? (L+1) : 0;   // L==3: h write is dead but harmless
    gemm_bt<3,128,256><<<dim3(NROWS/128, 1), 512, 0, stream>>>(
        ffb, w2_t + (long)L*EMB*FFD, NROWS, EMB, FFD,
        b2 + L*EMB, x, x, h_buf,
        ln1g + Ln*EMB, ln1b + Ln*EMB);
  }
}